// Round 3
// baseline (313.099 us; speedup 1.0000x reference)
//
#include <hip/hip_runtime.h>
#include <cstdint>
#include <cstddef>

// BitLinear inference, round 3: fused activation-quant + barrier-free i8 GEMM.
// - Grid = 256 blocks (one per 128 M-rows), 512 threads (8 waves).
// - Phase A: quantize x-rows into a 128-row LDS A-panel (padded stride 1040 B
//   -> 2-way-free LDS banks). One __syncthreads total.
// - Phase B: 8 N-chunks of 128; A-frags from LDS, B-frags global-direct from
//   the 1 MB L2-resident wq. ZERO barriers in the K-loop (AITER-style).
// x_q in [-128,127], w_q in {-1,0,1}: i32 MFMA accumulation is exact.
//
// ws layout (bytes):
//   [0    .. 16)       red[4] = {sum_w, sumabs_w, sum_b, sumabs_b}
//   [1024 .. 1049600)  w_q int8 [1024*1024]

typedef __attribute__((ext_vector_type(4))) int int4v;

static constexpr int DIM = 1024;     // inner dim K
static constexpr int OUTF = 1024;    // output features N
static constexpr int MROWS = 32768;  // B*S
static constexpr float INV_WN = 1.0f / (1024.0f * 1024.0f);
static constexpr float INV_BN = 1.0f / 1024.0f;

#define OFF_WQ 1024
#define SP 1040  // LDS A-panel row stride in bytes (1024 + 16 pad)

__device__ inline float wave_sum(float v) {
#pragma unroll
  for (int off = 32; off; off >>= 1) v += __shfl_xor(v, off);
  return v;
}
__device__ inline float wave_max(float v) {
#pragma unroll
  for (int off = 32; off; off >>= 1) v = fmaxf(v, __shfl_xor(v, off));
  return v;
}

// ---------------------------------------------------------------- reductions
__global__ __launch_bounds__(256) void reduce_wb(const float* __restrict__ w,
                                                 const float* __restrict__ b,
                                                 float* __restrict__ red) {
  __shared__ float ss[4], sa[4];
  const int t = threadIdx.x;
  const int lane = t & 63, wv = t >> 6;
  float s = 0.0f, a = 0.0f;
  const float4* w4 = (const float4*)w;
  const int idx = blockIdx.x * 256 + t;
#pragma unroll
  for (int i = 0; i < 4; ++i) {
    float4 v = w4[idx + i * 65536];
    s += (v.x + v.y) + (v.z + v.w);
    a += (fabsf(v.x) + fabsf(v.y)) + (fabsf(v.z) + fabsf(v.w));
  }
  s = wave_sum(s);
  a = wave_sum(a);
  if (lane == 0) { ss[wv] = s; sa[wv] = a; }
  __syncthreads();
  if (t == 0) atomicAdd(&red[0], (ss[0] + ss[1]) + (ss[2] + ss[3]));
  if (t == 1) atomicAdd(&red[1], (sa[0] + sa[1]) + (sa[2] + sa[3]));
  if (blockIdx.x == 0) {
    __syncthreads();  // block-uniform branch, safe
    float4 v = ((const float4*)b)[t];
    float s2 = (v.x + v.y) + (v.z + v.w);
    float a2 = (fabsf(v.x) + fabsf(v.y)) + (fabsf(v.z) + fabsf(v.w));
    s2 = wave_sum(s2);
    a2 = wave_sum(a2);
    if (lane == 0) { ss[wv] = s2; sa[wv] = a2; }
    __syncthreads();
    if (t == 0) {
      red[2] = (ss[0] + ss[1]) + (ss[2] + ss[3]);
      red[3] = (sa[0] + sa[1]) + (sa[2] + sa[3]);
    }
  }
}

// ---------------------------------------------------------------- weight quant
__global__ __launch_bounds__(256) void quant_w(const float* __restrict__ w,
                                               const float* __restrict__ red,
                                               signed char* __restrict__ wq) {
  const float wmean = red[0] * INV_WN;
  const int idx = blockIdx.x * 256 + threadIdx.x;
  float4 v = ((const float4*)w)[idx];
  int q0, q1, q2, q3;
  float d;
  d = v.x - wmean; q0 = d > 0.f ? 1 : (d < 0.f ? -1 : 0);
  d = v.y - wmean; q1 = d > 0.f ? 1 : (d < 0.f ? -1 : 0);
  d = v.z - wmean; q2 = d > 0.f ? 1 : (d < 0.f ? -1 : 0);
  d = v.w - wmean; q3 = d > 0.f ? 1 : (d < 0.f ? -1 : 0);
  const int pk = (q0 & 0xff) | ((q1 & 0xff) << 8) | ((q2 & 0xff) << 16) | ((q3 & 0xff) << 24);
  ((int*)wq)[idx] = pk;
}

// ---------------------------------------------------------------- fused kernel
__global__ __launch_bounds__(512, 1) void fused_qx_gemm(
    const float* __restrict__ x,
    const signed char* __restrict__ wq,   // [N, K] i8, L2-resident (1 MB)
    const float* __restrict__ bias,
    const float* __restrict__ red,
    float* __restrict__ out) {
  __shared__ signed char As[128 * SP];  // 133,120 B quantized A-panel
  __shared__ float sxs[128];            // per-row int8 scales

  const int t = threadIdx.x;
  const int lane = t & 63;
  const int wv = t >> 6;  // 0..7
  const int quad = lane >> 4;
  const int r16 = lane & 15;
  const int bm = blockIdx.x;  // 0..255

  // ---------- phase A: quantize 16 rows per wave into the LDS A-panel
  {
    const int row0 = wv * 16;
    const float* xbase = x + ((size_t)bm * 128 + row0) * DIM;
    float4 v[4], vn[4];
#pragma unroll
    for (int j = 0; j < 4; ++j) v[j] = ((const float4*)xbase)[j * 64 + lane];

    for (int rr = 0; rr < 16; ++rr) {
      if (rr < 15) {  // software-pipelined prefetch of the next row
        const float4* xn = (const float4*)(xbase + (size_t)(rr + 1) * DIM);
#pragma unroll
        for (int j = 0; j < 4; ++j) vn[j] = xn[j * 64 + lane];
      }
      float ssq = 0.0f, ma = 0.0f;
#pragma unroll
      for (int j = 0; j < 4; ++j) {
        ssq += v[j].x * v[j].x + v[j].y * v[j].y + v[j].z * v[j].z + v[j].w * v[j].w;
        ma = fmaxf(ma, fmaxf(fmaxf(fabsf(v[j].x), fabsf(v[j].y)),
                             fmaxf(fabsf(v[j].z), fabsf(v[j].w))));
      }
      ssq = wave_sum(ssq);
      ma = wave_max(ma);

      const float l2 = sqrtf(ssq);
      const float inv = 0.03125f / fmaxf(l2, 1e-12f);       // dim_scale / max(l2,eps)
      const float scale = 127.0f / fmaxf(ma * inv, 1e-5f);  // per-token int8 scale
      const float f = inv * scale;

      const int rl = row0 + rr;
#pragma unroll
      for (int j = 0; j < 4; ++j) {
        const int q0 = (int)fminf(fmaxf(rintf(v[j].x * f), -128.f), 127.f);
        const int q1 = (int)fminf(fmaxf(rintf(v[j].y * f), -128.f), 127.f);
        const int q2 = (int)fminf(fmaxf(rintf(v[j].z * f), -128.f), 127.f);
        const int q3 = (int)fminf(fmaxf(rintf(v[j].w * f), -128.f), 127.f);
        *(int*)(As + rl * SP + j * 256 + lane * 4) =
            (q0 & 0xff) | ((q1 & 0xff) << 8) | ((q2 & 0xff) << 16) | ((q3 & 0xff) << 24);
      }
      if (lane == 0) sxs[rl] = scale;
#pragma unroll
      for (int j = 0; j < 4; ++j) v[j] = vn[j];
    }
  }
  __syncthreads();  // the ONLY barrier

  // ---------- phase B: barrier-free GEMM over 8 N-chunks
  const float wscale = red[1] * INV_WN;
  const float bscale = red[3] * INV_BN;
  const float bmean = red[2] * INV_BN;
  const float wb = wscale * bscale;

  const int wm2 = wv >> 2;  // 0..1 -> m offset *64
  const int wn2 = wv & 3;   // 0..3 -> n offset *32

  float rec[4][4];
#pragma unroll
  for (int i = 0; i < 4; ++i)
#pragma unroll
    for (int rr = 0; rr < 4; ++rr)
      rec[i][rr] = 1.0f / (wb * sxs[wm2 * 64 + i * 16 + quad * 4 + rr]);

  const signed char* AsW = As + (wm2 * 64 + r16) * SP + quad * 16;

  for (int nc = 0; nc < 8; ++nc) {
    int4v acc[4][2] = {};
    const signed char* Bb =
        wq + ((size_t)(nc * 128 + wn2 * 32 + r16)) * DIM + quad * 16;
#pragma unroll 4
    for (int ks = 0; ks < 16; ++ks) {  // K=64 per step, no barriers
      int4v af[4], bf[2];
#pragma unroll
      for (int i = 0; i < 4; ++i)
        af[i] = *(const int4v*)(AsW + i * 16 * SP + ks * 64);
#pragma unroll
      for (int j = 0; j < 2; ++j)
        bf[j] = *(const int4v*)(Bb + (size_t)j * 16 * DIM + ks * 64);
#pragma unroll
      for (int i = 0; i < 4; ++i)
#pragma unroll
        for (int j = 0; j < 2; ++j)
          acc[i][j] = __builtin_amdgcn_mfma_i32_16x16x64_i8(af[i], bf[j], acc[i][j], 0, 0, 0);
    }
    // epilogue for this N-chunk: ternary bias + dequant
#pragma unroll
    for (int j = 0; j < 2; ++j) {
      const int n = nc * 128 + wn2 * 32 + j * 16 + r16;
      const float bd = bias[n] - bmean;
      const int bq = bd > 0.f ? 1 : (bd < 0.f ? -1 : 0);
#pragma unroll
      for (int i = 0; i < 4; ++i) {
        const int mg = bm * 128 + wm2 * 64 + i * 16 + quad * 4;
        float* po = out + (size_t)mg * OUTF + n;
#pragma unroll
        for (int rr = 0; rr < 4; ++rr)
          po[(size_t)rr * OUTF] = (float)(acc[i][j][rr] + bq) * rec[i][rr];
      }
    }
  }
}

extern "C" void kernel_launch(void* const* d_in, const int* in_sizes, int n_in,
                              void* d_out, int out_size, void* d_ws, size_t ws_size,
                              hipStream_t stream) {
  const float* x = (const float*)d_in[0];
  const float* w = (const float*)d_in[1];
  const float* b = (const float*)d_in[2];
  float* out = (float*)d_out;
  char* ws = (char*)d_ws;

  float* red = (float*)ws;
  signed char* wq = (signed char*)(ws + OFF_WQ);

  hipMemsetAsync(red, 0, 4 * sizeof(float), stream);
  reduce_wb<<<256, 256, 0, stream>>>(w, b, red);
  quant_w<<<1024, 256, 0, stream>>>(w, red, wq);
  fused_qx_gemm<<<MROWS / 128, 512, 0, stream>>>(x, wq, b, red, out);
}